// Round 9
// baseline (212.617 us; speedup 1.0000x reference)
//
#include <hip/hip_runtime.h>
#include <math.h>

#define BB 2
#define TT 2048
#define EE 1024
#define HH 16
#define DD 64
#define MM (BB*TT)   // 4096
#define KK EE        // 1024

typedef short bf16x8 __attribute__((ext_vector_type(8)));
typedef float f32x4  __attribute__((ext_vector_type(4)));

// round-to-nearest-even fp32 -> bf16 (as ushort)
__device__ __forceinline__ unsigned short f2bf(float f) {
  unsigned int u = __float_as_uint(f);
  u = (u + 0x7FFFu + ((u >> 16) & 1u)) >> 16;
  return (unsigned short)u;
}

// async global->LDS DMA, 16B per lane, LDS dest = wave-uniform base + lane*16
__device__ __forceinline__ void async16(const void* g, void* l) {
  __builtin_amdgcn_global_load_lds(
      (const __attribute__((address_space(1))) unsigned int*)g,
      (__attribute__((address_space(3))) unsigned int*)l, 16, 0, 0);
}

// ---------------------------------------------------------------------------
// fp32 -> bf16 convert for x and the 4 weight matrices (Wq/Wk/Wv concatenated
// row-wise into one [3072 x 1024] buffer for the fused QKV GEMM).
// ---------------------------------------------------------------------------
__global__ __launch_bounds__(256) void to_bf16(
    const float* __restrict__ x,  const float* __restrict__ wq,
    const float* __restrict__ wk, const float* __restrict__ wv,
    const float* __restrict__ wo,
    unsigned short* __restrict__ xh, unsigned short* __restrict__ wcat,
    unsigned short* __restrict__ woh)
{
  int c = blockIdx.x * 256 + threadIdx.x;
  const float* src; unsigned short* dst; int off;
  if (c < 1048576) { src = x; dst = xh; off = c; }
  else {
    int r = c - 1048576;
    int w = r >> 18;                 // 262144 chunks per W
    off = r & 262143;
    if      (w == 0) { src = wq; dst = wcat; }
    else if (w == 1) { src = wk; dst = wcat + (1 << 20); }
    else if (w == 2) { src = wv; dst = wcat + (2 << 20); }
    else             { src = wo; dst = woh; }
  }
  float4 v = ((const float4*)src)[off];
  ushort4 h;
  h.x = f2bf(v.x); h.y = f2bf(v.y); h.z = f2bf(v.z); h.w = f2bf(v.w);
  ((ushort4*)dst)[off] = h;
}

// ---------------------------------------------------------------------------
// bf16 MFMA GEMM, flash-style double-buffered K-loop (single barrier/iter,
// prefetch in flight under compute): C[m,n] = A[m,:] . B[n,:] + bias[n].
// MODE 0: fused QKV, tile 128x128, N=3072, region by n0: Q (*qscale) / K
//         -> bf16 [b,h,t,d]; V -> bf16 [b,h,d,t]. Epilogue bounces C-tile
//         through LDS (aliased over the dead double-buffer) for 16B stores.
// MODE 2: fp32 out [m,EE], tile 128x64, direct dword stores.
// Staging: global_load_lds, XOR chunk swizzle (2-way banks = free).
// LDS buffer addresses computed arithmetically (no LDS pointer arrays —
// addrspacecast static initializers don't compile on gfx950).
// ---------------------------------------------------------------------------
template<int MODE>
__global__ __launch_bounds__(256) void gemm_bf16(
    const unsigned short* __restrict__ A, const unsigned short* __restrict__ B,
    const float* __restrict__ b0p, const float* __restrict__ b1p,
    const float* __restrict__ b2p,
    unsigned short* __restrict__ oq, unsigned short* __restrict__ ok,
    unsigned short* __restrict__ ov, float* __restrict__ ofp, float qscale)
{
  constexpr int NT = (MODE == 0) ? 128 : 64;   // n-tile
  constexpr int JN = NT / 32;                  // j-frags per wave
  constexpr int BROWS = NT * 32;               // B-buffer ushorts per stage
  // MODE 0: dbuf 2*4096 (A) + 2*4096 (B) = 16384; Cs alias needs 17408
  // MODE 2: dbuf 2*4096 + 2*2048 = 12288
  __shared__ unsigned short S[(MODE == 0) ? 17408 : 12288];

  const int tid  = threadIdx.x;
  const int lane = tid & 63;
  const int wv   = tid >> 6;
  const int col  = lane & 15;
  const int quad = lane >> 4;
  const int wm = (wv >> 1) * 64;
  const int wn = (wv & 1) * (NT / 2);
  const int m0 = blockIdx.x * 128;
  const int n0 = blockIdx.y * NT;

  const int srow = lane >> 2;                                // 16 rows/call
  const int sw16 = (((lane & 3) ^ ((lane >> 2) & 3)) << 3);  // ushort units
  const int fswA = ((quad ^ (col & 3)) << 3);                // frag slot

  constexpr int NW = (MODE == 0) ? 4 : 3;      // staging chunks per wave
  auto stage = [&](int kt, int b) {
#pragma unroll
    for (int s = 0; s < NW; ++s) {
      const int t = wv * NW + s;
      const unsigned short* src; int rb, g0, loff;
      if (t < 8) { src = A; rb = t * 16;       g0 = m0; loff = b * 4096; }
      else       { src = B; rb = (t - 8) * 16; g0 = n0; loff = 8192 + b * BROWS; }
      async16(src + (size_t)(g0 + rb + srow) * KK + kt + sw16,
              S + loff + rb * 32);
    }
  };

  f32x4 acc[4][JN];
  const f32x4 z = {0.f, 0.f, 0.f, 0.f};
#pragma unroll
  for (int i = 0; i < 4; ++i)
#pragma unroll
    for (int j = 0; j < JN; ++j) acc[i][j] = z;

  stage(0, 0);
  __syncthreads();     // only iter-0's latency is exposed

  for (int kt = 0; kt < KK; kt += 32) {
    const int buf = (kt >> 5) & 1;
    if (kt + 32 < KK) stage(kt + 32, buf ^ 1);   // prefetch under compute

    const unsigned short* Asb = S + buf * 4096;
    const unsigned short* Bsb = S + 8192 + buf * BROWS;
    bf16x8 bf[JN];
#pragma unroll
    for (int j = 0; j < JN; ++j)
      bf[j] = *(const bf16x8*)(Bsb + (wn + j * 16 + col) * 32 + fswA);
#pragma unroll
    for (int i = 0; i < 4; ++i) {
      bf16x8 af = *(const bf16x8*)(Asb + (wm + i * 16 + col) * 32 + fswA);
#pragma unroll
      for (int j = 0; j < JN; ++j)
        acc[i][j] = __builtin_amdgcn_mfma_f32_16x16x32_bf16(af, bf[j], acc[i][j], 0, 0, 0);
    }
    __syncthreads();   // drains prefetch vmcnt + frag reads of buf
  }

  // Epilogue. C/D: row = quad*4+r, col = lane&15 per 16x16 tile.
  // (loop-end barrier guarantees all frag reads done -> Cs alias safe)
  unsigned short* Cs = S;
  if (MODE == 0) {
    const int region = n0 >> 10;   // block-uniform: 0=Q, 1=K, 2=V
    const float* bias = (region == 0) ? b0p : (region == 1) ? b1p : b2p;
    const float scl = (region == 0) ? qscale : 1.0f;
    const int nlbase = n0 & 1023;
    const int h0 = nlbase >> 6;
    const int b = m0 >> 11, t0 = m0 & (TT - 1);
    if (region < 2) {
      // Cs[m][n] (stride 136): scalar bf16 writes, coalesced row reads.
#pragma unroll
      for (int i = 0; i < 4; ++i)
#pragma unroll
        for (int j = 0; j < 4; ++j) {
          const int nt = wn + j * 16 + col;
          const float bs = bias[nlbase + nt];
#pragma unroll
          for (int r = 0; r < 4; ++r) {
            const int mt = wm + i * 16 + quad * 4 + r;
            Cs[mt * 136 + nt] = f2bf((acc[i][j][r] + bs) * scl);
          }
        }
      __syncthreads();
      unsigned short* dst = (region == 0) ? oq : ok;
#pragma unroll
      for (int s = 0; s < 8; ++s) {
        const int u = s * 256 + tid;          // 2048 units: 128m x 2h x 8ch
        const int mt = u >> 4, hs = (u >> 3) & 1, ch = u & 7;
        const size_t g = ((size_t)(b * HH + h0 + hs) * TT + t0 + mt) * DD + ch * 8;
        *(uint4*)(dst + g) = *(const uint4*)(Cs + mt * 136 + hs * 64 + ch * 8);
      }
    } else {
      // V: Cs[n][m] (stride 136): packed b64 writes, coalesced row reads.
#pragma unroll
      for (int i = 0; i < 4; ++i)
#pragma unroll
        for (int j = 0; j < 4; ++j) {
          const int nt = wn + j * 16 + col;
          const float bs = bias[nlbase + nt];
          ushort4 pk;
          pk.x = f2bf(acc[i][j][0] + bs);
          pk.y = f2bf(acc[i][j][1] + bs);
          pk.z = f2bf(acc[i][j][2] + bs);
          pk.w = f2bf(acc[i][j][3] + bs);
          *(ushort4*)(Cs + nt * 136 + wm + i * 16 + quad * 4) = pk;
        }
      __syncthreads();
#pragma unroll
      for (int s = 0; s < 8; ++s) {
        const int u = s * 256 + tid;          // 2048 units: 128n x 16ch(m)
        const int nt = u >> 4, ch = u & 15;
        const int d = nt & 63, hs = nt >> 6;
        const size_t g = ((size_t)(b * HH + h0 + hs) * DD + d) * TT + t0 + ch * 8;
        *(uint4*)(ov + g) = *(const uint4*)(Cs + nt * 136 + ch * 8);
      }
    }
  } else {
#pragma unroll
    for (int i = 0; i < 4; ++i) {
#pragma unroll
      for (int j = 0; j < JN; ++j) {
        const int n = n0 + wn + j * 16 + col;
        const float bs = b0p[n];
#pragma unroll
        for (int r = 0; r < 4; ++r) {
          const int m = m0 + wm + i * 16 + quad * 4 + r;
          ofp[(size_t)m * EE + n] = acc[i][j][r] + bs;
        }
      }
    }
  }
}

// ---------------------------------------------------------------------------
// MFMA flash attention, max-free softmax (Q pre-scaled by log2e/8, p=2^s).
// S computed transposed (A=K, B=Q): each lane's C-frag holds 4 consecutive
// k values -> P packs via v_perm_b32 + ds_write_b64; l reduced in epilogue.
// K/V double-buffered; prefetch issued right after the per-iter barrier.
// Epilogue bounces ctx through the dead K/V LDS for coalesced 16B stores.
// ---------------------------------------------------------------------------
__global__ __launch_bounds__(256) void flash_mfma(
    const unsigned short* __restrict__ Qb, const unsigned short* __restrict__ Kb,
    const unsigned short* __restrict__ Vtb, unsigned short* __restrict__ ctx)
{
  __shared__ unsigned short QPs[128 * 72];     // Q: stride 64; P: stride 72
  __shared__ unsigned short Ks[2][64 * 64];
  __shared__ unsigned short Vts[2][64 * 64];

  const int tid  = threadIdx.x;
  const int lane = tid & 63;
  const int wv   = tid >> 6;
  const int col  = lane & 15;
  const int quad = lane >> 4;
  const int wm   = wv * 32;
  const int q0   = blockIdx.x * 128;
  const int bh   = blockIdx.y;

  const unsigned short* Qg = Qb  + (size_t)bh * TT * DD;
  const unsigned short* Kg = Kb  + (size_t)bh * TT * DD;
  const unsigned short* Vg = Vtb + (size_t)bh * DD * TT;

  const int srow = lane >> 3;                                // 8 rows/call
  const int sw16 = (((lane & 7) ^ ((lane >> 3) & 7)) << 3);  // ushort units
  const int cxor = (col & 7);

  auto stage_kv = [&](int kt, int b) {
#pragma unroll
    for (int s = 0; s < 4; ++s) {
      const int rb = (wv & 1) * 32 + s * 8;
      if (wv < 2)
        async16(Kg + (size_t)(kt + rb + srow) * DD + sw16, &Ks[b][rb * 64]);
      else
        async16(Vg + (size_t)(rb + srow) * TT + kt + sw16, &Vts[b][rb * 64]);
    }
  };

  // stage Q (128x64) + K/V tile 0
#pragma unroll
  for (int s = 0; s < 4; ++s) {
    const int rb = wv * 32 + s * 8;
    async16(Qg + (size_t)(q0 + rb + srow) * DD + sw16, &QPs[rb * 64]);
  }
  stage_kv(0, 0);
  __syncthreads();

  // hoist Q fragments (B-operand for S^T)
  bf16x8 aq[2][2];
#pragma unroll
  for (int i = 0; i < 2; ++i)
#pragma unroll
    for (int h = 0; h < 2; ++h)
      aq[i][h] = *(const bf16x8*)(QPs + (wm + i * 16 + col) * 64 +
                                  (((h * 4 + quad) ^ cxor) << 3));
  __syncthreads();   // all waves hoisted Q before P writes clobber QPs

  f32x4 o_acc[2][4];
  float lpart[2];
  const f32x4 z = {0.f, 0.f, 0.f, 0.f};
#pragma unroll
  for (int i = 0; i < 2; ++i) {
    lpart[i] = 0.f;
#pragma unroll
    for (int j = 0; j < 4; ++j) o_acc[i][j] = z;
  }

  for (int kt = 0; kt < TT; kt += 64) {
    const int buf = (kt >> 6) & 1;
    if (kt + 64 < TT) stage_kv(kt + 64, buf ^ 1);   // prefetch next tile

    // S^T = K.Q^T : sacc[i][j] lane(c,q) reg r = P[qrow wm+16i+c][k 16j+4q+r]
    f32x4 sacc[2][4];
#pragma unroll
    for (int i = 0; i < 2; ++i)
#pragma unroll
      for (int j = 0; j < 4; ++j) sacc[i][j] = z;

#pragma unroll
    for (int j = 0; j < 4; ++j) {
      bf16x8 bk0 = *(const bf16x8*)(Ks[buf] + (j * 16 + col) * 64 + ((quad ^ cxor) << 3));
      bf16x8 bk1 = *(const bf16x8*)(Ks[buf] + (j * 16 + col) * 64 + (((4 + quad) ^ cxor) << 3));
#pragma unroll
      for (int i = 0; i < 2; ++i) {
        sacc[i][j] = __builtin_amdgcn_mfma_f32_16x16x32_bf16(bk0, aq[i][0], sacc[i][j], 0, 0, 0);
        sacc[i][j] = __builtin_amdgcn_mfma_f32_16x16x32_bf16(bk1, aq[i][1], sacc[i][j], 0, 0, 0);
      }
    }

    // softmax: p = 2^s; pack pairs with v_perm (truncation; bias cancels in
    // the softmax ratio) -> one ds_write_b64 per 4 consecutive-k values.
#pragma unroll
    for (int i = 0; i < 2; ++i) {
      const int prow = (wm + i * 16 + col) * 72;
      float lp = 0.f;
#pragma unroll
      for (int j = 0; j < 4; ++j) {
        float p0 = __builtin_amdgcn_exp2f(sacc[i][j][0]);
        float p1 = __builtin_amdgcn_exp2f(sacc[i][j][1]);
        float p2 = __builtin_amdgcn_exp2f(sacc[i][j][2]);
        float p3 = __builtin_amdgcn_exp2f(sacc[i][j][3]);
        lp += (p0 + p1) + (p2 + p3);
        uint2 w;
        w.x = __builtin_amdgcn_perm(__float_as_uint(p1), __float_as_uint(p0), 0x07060302u);
        w.y = __builtin_amdgcn_perm(__float_as_uint(p3), __float_as_uint(p2), 0x07060302u);
        *(uint2*)(QPs + prow + j * 16 + quad * 4) = w;
      }
      lpart[i] += lp;
    }

    // hoist P A-frags (wave-private rows; in-wave lgkm ordering)
    bf16x8 ap[2][2];
#pragma unroll
    for (int i = 0; i < 2; ++i) {
      ap[i][0] = *(const bf16x8*)(QPs + (wm + i * 16 + col) * 72 + quad * 8);
      ap[i][1] = *(const bf16x8*)(QPs + (wm + i * 16 + col) * 72 + 32 + quad * 8);
    }

    // O += P V
#pragma unroll
    for (int j = 0; j < 4; ++j) {
      bf16x8 bv0 = *(const bf16x8*)(Vts[buf] + (j * 16 + col) * 64 + ((quad ^ cxor) << 3));
      bf16x8 bv1 = *(const bf16x8*)(Vts[buf] + (j * 16 + col) * 64 + (((4 + quad) ^ cxor) << 3));
#pragma unroll
      for (int i = 0; i < 2; ++i) {
        o_acc[i][j] = __builtin_amdgcn_mfma_f32_16x16x32_bf16(ap[i][0], bv0, o_acc[i][j], 0, 0, 0);
        o_acc[i][j] = __builtin_amdgcn_mfma_f32_16x16x32_bf16(ap[i][1], bv1, o_acc[i][j], 0, 0, 0);
      }
    }

    __syncthreads();   // drains prefetch vmcnt + all LDS reads of buf
  }

  // Epilogue: reduce l over quads, normalize, bounce ctx through dead K LDS
  // (XOR chunk swizzle on writes), then coalesced 16B stores.
  unsigned short* Cs = &Ks[0][0];   // 16 KB = 128 x 64
  const int b = bh >> 4, h = bh & 15;
#pragma unroll
  for (int i = 0; i < 2; ++i) {
    float l = lpart[i];
    l += __shfl_xor(l, 16);
    l += __shfl_xor(l, 32);
#pragma unroll
    for (int r = 0; r < 4; ++r) {
      const float inv = 1.0f / __shfl(l, quad * 4 + r);
      const int trow = wm + i * 16 + quad * 4 + r;   // 0..127
#pragma unroll
      for (int j = 0; j < 4; ++j) {
        const int n = j * 16 + col;
        const int ch = ((n >> 3) ^ (trow & 7)) << 3;
        Cs[trow * 64 + ch + (n & 7)] = f2bf(o_acc[i][j][r] * inv);
      }
    }
  }
  __syncthreads();
#pragma unroll
  for (int s = 0; s < 4; ++s) {
    const int u = s * 256 + tid;        // 1024 units: 128 rows x 8 chunks
    const int mr = u >> 3, ch = u & 7;
    const size_t g = ((size_t)(b * TT + q0 + mr)) * EE + h * DD + ch * 8;
    const int chs = (ch ^ (mr & 7)) << 3;
    *(uint4*)(ctx + g) = *(const uint4*)(Cs + mr * 64 + chs);
  }
}

// ---------------------------------------------------------------------------
extern "C" void kernel_launch(void* const* d_in, const int* in_sizes, int n_in,
                              void* d_out, int out_size, void* d_ws, size_t ws_size,
                              hipStream_t stream) {
  const float* x  = (const float*)d_in[0];
  const float* Wq = (const float*)d_in[1];
  const float* bq = (const float*)d_in[2];
  const float* Wk = (const float*)d_in[3];
  const float* bk = (const float*)d_in[4];
  const float* Wv = (const float*)d_in[5];
  const float* bv = (const float*)d_in[6];
  const float* Wo = (const float*)d_in[7];
  const float* bo = (const float*)d_in[8];

  unsigned short* p = (unsigned short*)d_ws;
  const size_t XN = (size_t)MM * EE;   // 4M
  const size_t WN = (size_t)EE * EE;   // 1M
  unsigned short* x_h    = p;           p += XN;
  unsigned short* Wcat_h = p;           p += 3 * WN;  // Wq||Wk||Wv rows
  unsigned short* Wo_h   = p;           p += WN;
  unsigned short* Qb     = p;           p += XN;
  unsigned short* Kb     = p;           p += XN;
  unsigned short* Vtb    = p;           p += XN;
  unsigned short* ctx_h  = x_h;         // x_h dead after QKV GEMM

  to_bf16<<<8192, 256, 0, stream>>>(x, Wq, Wk, Wv, Wo, x_h, Wcat_h, Wo_h);

  const float qscale = 0.125f * 1.44269504088896f;   // fold log2e for exp2

  gemm_bf16<0><<<dim3(MM / 128, 3 * EE / 128), 256, 0, stream>>>(
      x_h, Wcat_h, bq, bk, bv, Qb, Kb, Vtb, nullptr, qscale);

  flash_mfma<<<dim3(TT / 128, BB * HH), 256, 0, stream>>>(Qb, Kb, Vtb, ctx_h);

  gemm_bf16<2><<<dim3(MM / 128, EE / 64), 256, 0, stream>>>(
      ctx_h, Wo_h, bo, nullptr, nullptr,
      nullptr, nullptr, nullptr, (float*)d_out, 1.0f);
}

// Round 10
// 193.311 us; speedup vs baseline: 1.0999x; 1.0999x over previous
//
#include <hip/hip_runtime.h>
#include <math.h>

#define BB 2
#define TT 2048
#define EE 1024
#define HH 16
#define DD 64
#define MM (BB*TT)   // 4096
#define KK EE        // 1024

typedef short bf16x8 __attribute__((ext_vector_type(8)));
typedef float f32x4  __attribute__((ext_vector_type(4)));

// round-to-nearest-even fp32 -> bf16 (as ushort)
__device__ __forceinline__ unsigned short f2bf(float f) {
  unsigned int u = __float_as_uint(f);
  u = (u + 0x7FFFu + ((u >> 16) & 1u)) >> 16;
  return (unsigned short)u;
}

// async global->LDS DMA, 16B per lane, LDS dest = wave-uniform base + lane*16
__device__ __forceinline__ void async16(const void* g, void* l) {
  __builtin_amdgcn_global_load_lds(
      (const __attribute__((address_space(1))) unsigned int*)g,
      (__attribute__((address_space(3))) unsigned int*)l, 16, 0, 0);
}

// ---------------------------------------------------------------------------
// fp32 -> bf16 convert for x and the 4 weight matrices (Wq/Wk/Wv concatenated
// row-wise into one [3072 x 1024] buffer for the fused QKV GEMM).
// ---------------------------------------------------------------------------
__global__ __launch_bounds__(256) void to_bf16(
    const float* __restrict__ x,  const float* __restrict__ wq,
    const float* __restrict__ wk, const float* __restrict__ wv,
    const float* __restrict__ wo,
    unsigned short* __restrict__ xh, unsigned short* __restrict__ wcat,
    unsigned short* __restrict__ woh)
{
  int c = blockIdx.x * 256 + threadIdx.x;
  const float* src; unsigned short* dst; int off;
  if (c < 1048576) { src = x; dst = xh; off = c; }
  else {
    int r = c - 1048576;
    int w = r >> 18;                 // 262144 chunks per W
    off = r & 262143;
    if      (w == 0) { src = wq; dst = wcat; }
    else if (w == 1) { src = wk; dst = wcat + (1 << 20); }
    else if (w == 2) { src = wv; dst = wcat + (2 << 20); }
    else             { src = wo; dst = woh; }
  }
  float4 v = ((const float4*)src)[off];
  ushort4 h;
  h.x = f2bf(v.x); h.y = f2bf(v.y); h.z = f2bf(v.z); h.w = f2bf(v.w);
  ((ushort4*)dst)[off] = h;
}

// ---------------------------------------------------------------------------
// bf16 MFMA GEMM, 512 threads / 8 waves (4m x 2n wave grid, 32-row wave
// tiles) for TLP: latency is covered by 4+ waves/SIMD, not ILP (barrier
// drains any in-flight global_load_lds — m97 barrier-drain).
// MODE 0: fused QKV, tile 128x128, N=3072, region by n0: Q (*qscale) / K
//         -> bf16 [b,h,t,d]; V -> bf16 [b,h,d,t]. Epilogue bounces C-tile
//         through LDS (aliased over the dead double-buffer) for 16B stores.
// MODE 2: fp32 out [m,EE], tile 128x64, direct dword stores.
// ---------------------------------------------------------------------------
template<int MODE>
__global__ __launch_bounds__(512) void gemm_bf16(
    const unsigned short* __restrict__ A, const unsigned short* __restrict__ B,
    const float* __restrict__ b0p, const float* __restrict__ b1p,
    const float* __restrict__ b2p,
    unsigned short* __restrict__ oq, unsigned short* __restrict__ ok,
    unsigned short* __restrict__ ov, float* __restrict__ ofp, float qscale)
{
  constexpr int NT = (MODE == 0) ? 128 : 64;   // n-tile
  constexpr int JN = NT / 32;                  // j-frags per wave (4 / 2)
  constexpr int BROWS = NT * 32;               // B-buffer ushorts per stage
  constexpr int TOT = (MODE == 0) ? 16 : 12;   // staging chunks per iter
  // MODE 0: dbuf 2*4096 (A) + 2*4096 (B) = 16384; Cs alias needs 17408
  __shared__ unsigned short S[(MODE == 0) ? 17408 : 12288];

  const int tid  = threadIdx.x;
  const int lane = tid & 63;
  const int wv   = tid >> 6;                   // 0..7
  const int col  = lane & 15;
  const int quad = lane >> 4;
  const int wm = (wv & 3) * 32;
  const int wn = (wv >> 2) * (NT / 2);
  const int m0 = blockIdx.x * 128;
  const int n0 = blockIdx.y * NT;

  const int srow = lane >> 2;                                // 16 rows/call
  const int sw16 = (((lane & 3) ^ ((lane >> 2) & 3)) << 3);  // ushort units
  const int fswA = ((quad ^ (col & 3)) << 3);                // frag slot

  auto stage = [&](int kt, int b) {
#pragma unroll
    for (int s = 0; s < 2; ++s) {
      const int t = wv * 2 + s;
      if (t < TOT) {
        const unsigned short* src; int rb, g0, loff;
        if (t < 8) { src = A; rb = t * 16;       g0 = m0; loff = b * 4096; }
        else       { src = B; rb = (t - 8) * 16; g0 = n0; loff = 8192 + b * BROWS; }
        async16(src + (size_t)(g0 + rb + srow) * KK + kt + sw16,
                S + loff + rb * 32);
      }
    }
  };

  f32x4 acc[2][JN];
  const f32x4 z = {0.f, 0.f, 0.f, 0.f};
#pragma unroll
  for (int i = 0; i < 2; ++i)
#pragma unroll
    for (int j = 0; j < JN; ++j) acc[i][j] = z;

  stage(0, 0);
  __syncthreads();

  for (int kt = 0; kt < KK; kt += 32) {
    const int buf = (kt >> 5) & 1;
    if (kt + 32 < KK) stage(kt + 32, buf ^ 1);

    const unsigned short* Asb = S + buf * 4096;
    const unsigned short* Bsb = S + 8192 + buf * BROWS;
    bf16x8 bf[JN];
#pragma unroll
    for (int j = 0; j < JN; ++j)
      bf[j] = *(const bf16x8*)(Bsb + (wn + j * 16 + col) * 32 + fswA);
#pragma unroll
    for (int i = 0; i < 2; ++i) {
      bf16x8 af = *(const bf16x8*)(Asb + (wm + i * 16 + col) * 32 + fswA);
#pragma unroll
      for (int j = 0; j < JN; ++j)
        acc[i][j] = __builtin_amdgcn_mfma_f32_16x16x32_bf16(af, bf[j], acc[i][j], 0, 0, 0);
    }
    __syncthreads();
  }

  // Epilogue. C/D: row = quad*4+r, col = lane&15 per 16x16 tile.
  unsigned short* Cs = S;
  if (MODE == 0) {
    const int region = n0 >> 10;   // block-uniform: 0=Q, 1=K, 2=V
    const float* bias = (region == 0) ? b0p : (region == 1) ? b1p : b2p;
    const float scl = (region == 0) ? qscale : 1.0f;
    const int nlbase = n0 & 1023;
    const int h0 = nlbase >> 6;
    const int b = m0 >> 11, t0 = m0 & (TT - 1);
    if (region < 2) {
      // Cs[m][n] (stride 136): scalar bf16 writes, coalesced row reads.
#pragma unroll
      for (int i = 0; i < 2; ++i)
#pragma unroll
        for (int j = 0; j < 4; ++j) {
          const int nt = wn + j * 16 + col;
          const float bs = bias[nlbase + nt];
#pragma unroll
          for (int r = 0; r < 4; ++r) {
            const int mt = wm + i * 16 + quad * 4 + r;
            Cs[mt * 136 + nt] = f2bf((acc[i][j][r] + bs) * scl);
          }
        }
      __syncthreads();
      unsigned short* dst = (region == 0) ? oq : ok;
#pragma unroll
      for (int s = 0; s < 4; ++s) {
        const int u = s * 512 + tid;          // 2048 units: 128m x 2h x 8ch
        const int mt = u >> 4, hs = (u >> 3) & 1, ch = u & 7;
        const size_t g = ((size_t)(b * HH + h0 + hs) * TT + t0 + mt) * DD + ch * 8;
        *(uint4*)(dst + g) = *(const uint4*)(Cs + mt * 136 + hs * 64 + ch * 8);
      }
    } else {
      // V: Cs[n][m] (stride 136): packed b64 writes, coalesced row reads.
#pragma unroll
      for (int i = 0; i < 2; ++i)
#pragma unroll
        for (int j = 0; j < 4; ++j) {
          const int nt = wn + j * 16 + col;
          const float bs = bias[nlbase + nt];
          ushort4 pk;
          pk.x = f2bf(acc[i][j][0] + bs);
          pk.y = f2bf(acc[i][j][1] + bs);
          pk.z = f2bf(acc[i][j][2] + bs);
          pk.w = f2bf(acc[i][j][3] + bs);
          *(ushort4*)(Cs + nt * 136 + wm + i * 16 + quad * 4) = pk;
        }
      __syncthreads();
#pragma unroll
      for (int s = 0; s < 4; ++s) {
        const int u = s * 512 + tid;          // 2048 units: 128n x 16ch(m)
        const int nt = u >> 4, ch = u & 15;
        const int d = nt & 63, hs = nt >> 6;
        const size_t g = ((size_t)(b * HH + h0 + hs) * DD + d) * TT + t0 + ch * 8;
        *(uint4*)(ov + g) = *(const uint4*)(Cs + nt * 136 + ch * 8);
      }
    }
  } else {
#pragma unroll
    for (int i = 0; i < 2; ++i) {
#pragma unroll
      for (int j = 0; j < JN; ++j) {
        const int n = n0 + wn + j * 16 + col;
        const float bs = b0p[n];
#pragma unroll
        for (int r = 0; r < 4; ++r) {
          const int m = m0 + wm + i * 16 + quad * 4 + r;
          ofp[(size_t)m * EE + n] = acc[i][j][r] + bs;
        }
      }
    }
  }
}

// ---------------------------------------------------------------------------
// MFMA flash attention, 512 threads / 8 waves (wave owns 16 q-rows) for TLP.
// Max-free softmax (Q pre-scaled by log2e/8, p=2^s). S computed transposed
// (A=K, B=Q): lane's C-frag holds 4 consecutive k -> v_perm pack +
// ds_write_b64; l reduced in epilogue. K/V double-buffered.
// 1-D grid with bh = gid&31: all q-tiles of one (b,h) share an XCD
// (gid%8 = bh%8) -> K/V stay in that XCD's L2.
// ---------------------------------------------------------------------------
__global__ __launch_bounds__(512) void flash_mfma(
    const unsigned short* __restrict__ Qb, const unsigned short* __restrict__ Kb,
    const unsigned short* __restrict__ Vtb, unsigned short* __restrict__ ctx)
{
  __shared__ unsigned short QPs[128 * 72];     // Q: stride 64; P: stride 72
  __shared__ unsigned short Ks[2][64 * 64];
  __shared__ unsigned short Vts[2][64 * 64];

  const int tid  = threadIdx.x;
  const int lane = tid & 63;
  const int wv   = tid >> 6;                   // 0..7
  const int col  = lane & 15;
  const int quad = lane >> 4;
  const int wm   = wv * 16;                    // wave's 16 q-rows
  const int gid  = blockIdx.x;
  const int bh   = gid & 31;                   // XCD = gid%8 = bh%8
  const int q0   = (gid >> 5) * 128;

  const unsigned short* Qg = Qb  + (size_t)bh * TT * DD;
  const unsigned short* Kg = Kb  + (size_t)bh * TT * DD;
  const unsigned short* Vg = Vtb + (size_t)bh * DD * TT;

  const int srow = lane >> 3;                                // 8 rows/call
  const int sw16 = (((lane & 7) ^ ((lane >> 3) & 7)) << 3);  // ushort units
  const int cxor = (col & 7);

  auto stage_kv = [&](int kt, int b) {
#pragma unroll
    for (int s = 0; s < 2; ++s) {
      const int rb = (wv & 3) * 16 + s * 8;
      if (wv < 4)
        async16(Kg + (size_t)(kt + rb + srow) * DD + sw16, &Ks[b][rb * 64]);
      else
        async16(Vg + (size_t)(rb + srow) * TT + kt + sw16, &Vts[b][rb * 64]);
    }
  };

  // stage Q (128x64) + K/V tile 0
#pragma unroll
  for (int s = 0; s < 2; ++s) {
    const int rb = wv * 16 + s * 8;
    async16(Qg + (size_t)(q0 + rb + srow) * DD + sw16, &QPs[rb * 64]);
  }
  stage_kv(0, 0);
  __syncthreads();

  // hoist Q fragments (B-operand for S^T)
  bf16x8 aq[2];
#pragma unroll
  for (int h = 0; h < 2; ++h)
    aq[h] = *(const bf16x8*)(QPs + (wm + col) * 64 +
                             (((h * 4 + quad) ^ cxor) << 3));
  __syncthreads();   // all waves hoisted Q before P writes clobber QPs

  f32x4 o_acc[4];
  float lpart = 0.f;
  const f32x4 z = {0.f, 0.f, 0.f, 0.f};
#pragma unroll
  for (int j = 0; j < 4; ++j) o_acc[j] = z;

  for (int kt = 0; kt < TT; kt += 64) {
    const int buf = (kt >> 6) & 1;
    if (kt + 64 < TT) stage_kv(kt + 64, buf ^ 1);   // prefetch next tile

    // S^T = K.Q^T : sacc[j] lane(c,q) reg r = P[qrow wm+c][k 16j+4q+r]
    f32x4 sacc[4];
#pragma unroll
    for (int j = 0; j < 4; ++j) sacc[j] = z;

#pragma unroll
    for (int j = 0; j < 4; ++j) {
      bf16x8 bk0 = *(const bf16x8*)(Ks[buf] + (j * 16 + col) * 64 + ((quad ^ cxor) << 3));
      bf16x8 bk1 = *(const bf16x8*)(Ks[buf] + (j * 16 + col) * 64 + (((4 + quad) ^ cxor) << 3));
      sacc[j] = __builtin_amdgcn_mfma_f32_16x16x32_bf16(bk0, aq[0], sacc[j], 0, 0, 0);
      sacc[j] = __builtin_amdgcn_mfma_f32_16x16x32_bf16(bk1, aq[1], sacc[j], 0, 0, 0);
    }

    // softmax: p = 2^s; v_perm pack -> one ds_write_b64 per 4 k values.
    {
      const int prow = (wm + col) * 72;
      float lp = 0.f;
#pragma unroll
      for (int j = 0; j < 4; ++j) {
        float p0 = __builtin_amdgcn_exp2f(sacc[j][0]);
        float p1 = __builtin_amdgcn_exp2f(sacc[j][1]);
        float p2 = __builtin_amdgcn_exp2f(sacc[j][2]);
        float p3 = __builtin_amdgcn_exp2f(sacc[j][3]);
        lp += (p0 + p1) + (p2 + p3);
        uint2 w;
        w.x = __builtin_amdgcn_perm(__float_as_uint(p1), __float_as_uint(p0), 0x07060302u);
        w.y = __builtin_amdgcn_perm(__float_as_uint(p3), __float_as_uint(p2), 0x07060302u);
        *(uint2*)(QPs + prow + j * 16 + quad * 4) = w;
      }
      lpart += lp;
    }

    // hoist P A-frags (wave-private rows; in-wave lgkm ordering)
    bf16x8 ap0 = *(const bf16x8*)(QPs + (wm + col) * 72 + quad * 8);
    bf16x8 ap1 = *(const bf16x8*)(QPs + (wm + col) * 72 + 32 + quad * 8);

    // O += P V
#pragma unroll
    for (int j = 0; j < 4; ++j) {
      bf16x8 bv0 = *(const bf16x8*)(Vts[buf] + (j * 16 + col) * 64 + ((quad ^ cxor) << 3));
      bf16x8 bv1 = *(const bf16x8*)(Vts[buf] + (j * 16 + col) * 64 + (((4 + quad) ^ cxor) << 3));
      o_acc[j] = __builtin_amdgcn_mfma_f32_16x16x32_bf16(ap0, bv0, o_acc[j], 0, 0, 0);
      o_acc[j] = __builtin_amdgcn_mfma_f32_16x16x32_bf16(ap1, bv1, o_acc[j], 0, 0, 0);
    }

    __syncthreads();   // drains prefetch vmcnt + all LDS reads of buf
  }

  // Epilogue: reduce l over quads, normalize, bounce ctx through dead K LDS
  // (XOR chunk swizzle on writes), then coalesced 16B stores.
  unsigned short* Cs = &Ks[0][0];   // 16 KB = 128 x 64
  const int b = bh >> 4, h = bh & 15;
  float l = lpart;
  l += __shfl_xor(l, 16);
  l += __shfl_xor(l, 32);
#pragma unroll
  for (int r = 0; r < 4; ++r) {
    const float inv = 1.0f / __shfl(l, quad * 4 + r);
    const int trow = wm + quad * 4 + r;   // 0..127
#pragma unroll
    for (int j = 0; j < 4; ++j) {
      const int n = j * 16 + col;
      const int ch = ((n >> 3) ^ (trow & 7)) << 3;
      Cs[trow * 64 + ch + (n & 7)] = f2bf(o_acc[j][r] * inv);
    }
  }
  __syncthreads();
#pragma unroll
  for (int s = 0; s < 2; ++s) {
    const int u = s * 512 + tid;        // 1024 units: 128 rows x 8 chunks
    const int mr = u >> 3, ch = u & 7;
    const size_t g = ((size_t)(b * TT + q0 + mr)) * EE + h * DD + ch * 8;
    const int chs = (ch ^ (mr & 7)) << 3;
    *(uint4*)(ctx + g) = *(const uint4*)(Cs + mr * 64 + chs);
  }
}

// ---------------------------------------------------------------------------
extern "C" void kernel_launch(void* const* d_in, const int* in_sizes, int n_in,
                              void* d_out, int out_size, void* d_ws, size_t ws_size,
                              hipStream_t stream) {
  const float* x  = (const float*)d_in[0];
  const float* Wq = (const float*)d_in[1];
  const float* bq = (const float*)d_in[2];
  const float* Wk = (const float*)d_in[3];
  const float* bk = (const float*)d_in[4];
  const float* Wv = (const float*)d_in[5];
  const float* bv = (const float*)d_in[6];
  const float* Wo = (const float*)d_in[7];
  const float* bo = (const float*)d_in[8];

  unsigned short* p = (unsigned short*)d_ws;
  const size_t XN = (size_t)MM * EE;   // 4M
  const size_t WN = (size_t)EE * EE;   // 1M
  unsigned short* x_h    = p;           p += XN;
  unsigned short* Wcat_h = p;           p += 3 * WN;  // Wq||Wk||Wv rows
  unsigned short* Wo_h   = p;           p += WN;
  unsigned short* Qb     = p;           p += XN;
  unsigned short* Kb     = p;           p += XN;
  unsigned short* Vtb    = p;           p += XN;
  unsigned short* ctx_h  = x_h;         // x_h dead after QKV GEMM

  to_bf16<<<8192, 256, 0, stream>>>(x, Wq, Wk, Wv, Wo, x_h, Wcat_h, Wo_h);

  const float qscale = 0.125f * 1.44269504088896f;   // fold log2e for exp2

  gemm_bf16<0><<<dim3(MM / 128, 3 * EE / 128), 512, 0, stream>>>(
      x_h, Wcat_h, bq, bk, bv, Qb, Kb, Vtb, nullptr, qscale);

  flash_mfma<<<dim3((TT / 128) * BB * HH), 512, 0, stream>>>(Qb, Kb, Vtb, ctx_h);

  gemm_bf16<2><<<dim3(MM / 128, EE / 64), 512, 0, stream>>>(
      ctx_h, Wo_h, bo, nullptr, nullptr,
      nullptr, nullptr, nullptr, (float*)d_out, 1.0f);
}